// Round 9
// baseline (46.564 us; speedup 1.0000x reference)
//
#include <hip/hip_runtime.h>

#define NBATCH 32
#define DIST 5.0f
#define EPSV 1e-6f
#define INV_SQRT_F 0.17677669529663687f   // 1/sqrt(32)
#define SC_STAGE2 1.72633492e-4f          // 32^{-5/2}
#define SL1 7     // stage-1 slices per batch -> 224 blocks (87% lane fill)
#define SL2 7     // stage-2 slices per batch -> 224 blocks

__device__ __forceinline__ float silu_f(float v) { return __fdividef(v, 1.0f + __expf(-v)); }

// monotonic float <-> uint mapping for min/max via integer compares
__device__ __forceinline__ unsigned f2key(float f) {
  unsigned u = __float_as_uint(f);
  return (u & 0x80000000u) ? ~u : (u | 0x80000000u);
}
__device__ __forceinline__ float key2f(unsigned k) {
  return (k & 0x80000000u) ? __uint_as_float(k ^ 0x80000000u) : __uint_as_float(~k);
}

// all-threads redundant binary search (no divergence, L2-cached probes)
__device__ __forceinline__ int lower_bound_i(const int* __restrict__ batch, int N, int key) {
  int lo = 0, hi = N;
  while (lo < hi) { int m = (lo + hi) >> 1; if (batch[m] < key) lo = m + 1; else hi = m; }
  return lo;
}

// ---------------- K1: stage-1 fused (bounds, z-scan, Mk, scores, exp, T/den slots) ----------------
extern "C" __global__ __launch_bounds__(256)
void stage1_kernel(const float* __restrict__ pos,
                   const int*   __restrict__ batch,
                   const float* __restrict__ xfeat,
                   const float* __restrict__ bw,
                   const float* __restrict__ Wqd,
                   const float* __restrict__ Wk1,
                   const float* __restrict__ Wk2,
                   const float* __restrict__ Wv1,
                   const float* __restrict__ Wdot,
                   const float* __restrict__ initd,
                   float* __restrict__ ws_Tp,    // [NB*SL1][512]
                   float* __restrict__ ws_denp,  // [NB*SL1][2]
                   float* __restrict__ ws_zf,    // [NB][2]
                   int N)
{
  const int b = blockIdx.x / SL1, jb = blockIdx.x % SL1;
  const int tid = threadIdx.x;

  __shared__ unsigned s_ru[256];
  __shared__ float s_red[256];
  __shared__ float s_bw[8];
  __shared__ float s_q[32], s_c[32];
  __shared__ float s_Wa[8][8], s_Wb[8][8];
  __shared__ float s_Mk[32][8];
  __shared__ float s_exh[256][17];   // pad 17: conflict-free reads
  __shared__ float s_xs[256][36];    // pad 36: float4 rows, conflict-free reads
  __shared__ float s_Tp[4][512];

  // (1) independent early work: small weight loads + q; (2) searches overlap via ILP
  if (tid < 8) s_bw[tid] = bw[tid];
  if (tid < 64) { s_Wa[tid >> 3][tid & 7] = Wk1[tid]; s_Wb[tid >> 3][tid & 7] = Wv1[tid]; }
  if (tid < 32) {
    float a = 0.f;
    #pragma unroll
    for (int f = 0; f < 32; f++) a += initd[f] * Wqd[f * 32 + tid];
    s_q[tid] = a * INV_SQRT_F;
  }
  const int ss0 = lower_bound_i(batch, N, b);
  const int ss1 = lower_bound_i(batch, N, b + 1);
  __syncthreads();
  if (tid < 32) {
    float a = 0.f;
    #pragma unroll
    for (int f = 0; f < 32; f++) a += s_q[f] * Wdot[f * 32 + tid];
    s_c[tid] = a;
  }
  __syncthreads();
  {
    int f = tid >> 3, h = tid & 7;
    const float* w = &Wk2[h * 1024 + f * 32];
    float a = 0.f;
    #pragma unroll
    for (int g = 0; g < 32; g++) a += w[g] * s_c[g];
    s_Mk[f][h] = a * (1.0f / 1024.0f);
  }

  // (3) batch-wide z min/max scan (syncs below also publish s_Mk)
  unsigned kmn = 0xFFFFFFFFu, kmx = 0u;
  for (int i = ss0 + tid; i < ss1; i += 256) {
    unsigned k = f2key(pos[3 * (size_t)i + 2]);
    kmn = min(kmn, k); kmx = max(kmx, k);
  }
  s_ru[tid] = kmn; __syncthreads();
  for (int off = 128; off > 0; off >>= 1) { if (tid < off) s_ru[tid] = min(s_ru[tid], s_ru[tid + off]); __syncthreads(); }
  const unsigned rmn = s_ru[0]; __syncthreads();
  s_ru[tid] = kmx; __syncthreads();
  for (int off = 128; off > 0; off >>= 1) { if (tid < off) s_ru[tid] = max(s_ru[tid], s_ru[tid + off]); __syncthreads(); }
  const unsigned rmx = s_ru[0];
  __syncthreads();
  const float zmin = key2f(rmn), zmax = key2f(rmx);

  const int cnt = ss1 - ss0;
  const int per = (cnt + SL1 - 1) / SL1;
  const int lo = ss0 + jb * per;
  const int hi = min(lo + per, ss1);

  float Treg[8] = {0,0,0,0,0,0,0,0};
  float d0 = 0.f, d1 = 0.f;
  const int group = tid >> 6, gt = tid & 63, osh = gt >> 2, ofg = gt & 3;

  for (int base = lo; base < hi; base += 256) {
    int i = base + tid;
    if (i < hi) {
      float z = pos[3 * (size_t)i + 2];
      float len0 = z - zmin + DIST, len1 = zmax + DIST - z;
      float xv[32];
      const float4* xp = (const float4*)&xfeat[(size_t)i * 32];
      float4* xso = (float4*)s_xs[tid];
      #pragma unroll
      for (int q = 0; q < 8; q++) {
        float4 t = xp[q];
        xso[q] = t;
        xv[4*q] = t.x; xv[4*q+1] = t.y; xv[4*q+2] = t.z; xv[4*q+3] = t.w;
      }
      float u[8] = {0,0,0,0,0,0,0,0};
      #pragma unroll
      for (int f = 0; f < 32; f++) {
        float xf = xv[f];
        #pragma unroll
        for (int h = 0; h < 8; h++) u[h] += xf * s_Mk[f][h];
      }
      #pragma unroll
      for (int s = 0; s < 2; s++) {
        float L = s ? len1 : len0;
        float inv = __fdividef(1.0f, L + EPSV);
        float ee[8];
        #pragma unroll
        for (int j = 0; j < 8; j++) ee[j] = __sinf(s_bw[j] * L) * inv;
        float sc = 0.f;
        #pragma unroll
        for (int h = 0; h < 8; h++) {
          float a = 0.f;
          #pragma unroll
          for (int j = 0; j < 8; j++) a += ee[j] * s_Wa[j][h];
          sc += silu_f(a) * u[h];
        }
        // softmax without max-subtraction (exact ratio; clamp = overflow guard)
        float ex = __expf(fminf(fmaxf(sc, -60.f), 60.f));
        if (s) d1 += ex; else d0 += ex;
        #pragma unroll
        for (int h = 0; h < 8; h++) {
          float v = 0.f;
          #pragma unroll
          for (int j = 0; j < 8; j++) v += ee[j] * s_Wb[j][h];
          s_exh[tid][8*s + h] = ex * silu_f(v);
        }
      }
    } else {
      #pragma unroll
      for (int h = 0; h < 16; h++) s_exh[tid][h] = 0.f;
      float4* xso = (float4*)s_xs[tid];
      float4 z4 = make_float4(0.f, 0.f, 0.f, 0.f);
      #pragma unroll
      for (int q = 0; q < 8; q++) xso[q] = z4;
    }
    __syncthreads();
    const int cb = group * 64;
    for (int c = cb; c < cb + 64; c++) {
      float eh = s_exh[c][osh];
      const float4* xr4 = (const float4*)&s_xs[c][ofg * 8];
      float4 xa = xr4[0], xb = xr4[1];
      Treg[0] += eh * xa.x; Treg[1] += eh * xa.y; Treg[2] += eh * xa.z; Treg[3] += eh * xa.w;
      Treg[4] += eh * xb.x; Treg[5] += eh * xb.y; Treg[6] += eh * xb.z; Treg[7] += eh * xb.w;
    }
    __syncthreads();
  }
  #pragma unroll
  for (int k = 0; k < 8; k++) s_Tp[group][osh * 32 + ofg * 8 + k] = Treg[k];
  __syncthreads();
  const int slot = b * SL1 + jb;
  for (int idx = tid; idx < 512; idx += 256)
    ws_Tp[slot * 512 + idx] = s_Tp[0][idx] + s_Tp[1][idx] + s_Tp[2][idx] + s_Tp[3][idx];
  s_red[tid] = d0; __syncthreads();
  for (int off = 128; off > 0; off >>= 1) { if (tid < off) s_red[tid] += s_red[tid + off]; __syncthreads(); }
  if (tid == 0) ws_denp[slot * 2 + 0] = s_red[0];
  __syncthreads();
  s_red[tid] = d1; __syncthreads();
  for (int off = 128; off > 0; off >>= 1) { if (tid < off) s_red[tid] += s_red[tid + off]; __syncthreads(); }
  if (tid == 0) ws_denp[slot * 2 + 1] = s_red[0];
  if (jb == 0 && tid == 0) { ws_zf[2*b] = zmin; ws_zf[2*b+1] = zmax; }
}

// ---------------- K2: per-batch tables (redundant per block) + stage-2 output ----------------
extern "C" __global__ __launch_bounds__(256)
void stage2_kernel(const float* __restrict__ pos,
                   const int*   __restrict__ batch,
                   const float* __restrict__ xfeat,
                   const float* __restrict__ bw,
                   const float* __restrict__ Wqg,  const float* __restrict__ Wdot,
                   const float* __restrict__ Wkg1, const float* __restrict__ Wkg2,
                   const float* __restrict__ Wvg1, const float* __restrict__ Wvg2,
                   const float* __restrict__ Wv2,  const float* __restrict__ initd,
                   const float* __restrict__ ws_Tp,
                   const float* __restrict__ ws_denp,
                   const float* __restrict__ ws_zf,
                   float* __restrict__ out_node, float* __restrict__ out_dummy,
                   int N)
{
  const int b = blockIdx.x / SL2, jb = blockIdx.x % SL2;
  const int tid = threadIdx.x;

  __shared__ float s_bw[8];
  __shared__ float s_Wa[8][8], s_Wb[8][8];
  __shared__ float s_T[512];
  __shared__ float s_den[2];
  __shared__ float s_dp[4][2][32];
  __shared__ float s_dm[2][32];
  __shared__ float s_WQD[32][32];
  __shared__ float s_Bkg[16][32];
  __shared__ float s_Bvg[16][32];
  __shared__ float s_G[32][16];

  // independent prologue work; searches overlap via ILP
  if (tid < 8) s_bw[tid] = bw[tid];
  if (tid < 64) { s_Wa[tid >> 3][tid & 7] = Wkg1[tid]; s_Wb[tid >> 3][tid & 7] = Wvg1[tid]; }
  if (tid < 2) {
    float d = 0.f;
    #pragma unroll
    for (int j = 0; j < SL1; j++) d += ws_denp[(b * SL1 + j) * 2 + tid];
    s_den[tid] = d;
  }
  for (int idx = tid; idx < 512; idx += 256) {
    float a = 0.f;
    #pragma unroll
    for (int j = 0; j < SL1; j++) a += ws_Tp[(b * SL1 + j) * 512 + idx];
    s_T[idx] = a;
  }
  for (int idx = tid; idx < 1024; idx += 256) {
    int f = idx >> 5, g = idx & 31;
    float a = 0.f;
    #pragma unroll
    for (int k = 0; k < 32; k++) a += Wqg[f * 32 + k] * Wdot[k * 32 + g];
    s_WQD[f][g] = a;
  }
  const int ss0 = lower_bound_i(batch, N, b);
  const int ss1 = lower_bound_i(batch, N, b + 1);
  const float zmin = ws_zf[2*b], zmax = ws_zf[2*b+1];
  __syncthreads();

  // parallel dummy: thread (fq, s, g) accumulates f in [fq*8, fq*8+8)
  {
    int g = tid & 31, s = (tid >> 5) & 1, fq = tid >> 6;
    float acc = 0.f;
    #pragma unroll
    for (int h = 0; h < 8; h++) {
      #pragma unroll
      for (int f8 = 0; f8 < 8; f8++) {
        int f = fq * 8 + f8;
        acc += s_T[(8 * s + h) * 32 + f] * Wv2[h * 1024 + f * 32 + g];
      }
    }
    s_dp[fq][s][g] = acc;
  }
  __syncthreads();
  if (tid < 64) {
    int s = tid >> 5, g = tid & 31;
    float acc = s_dp[0][s][g] + s_dp[1][s][g] + s_dp[2][s][g] + s_dp[3][s][g];
    float dn = s_den[s];
    float dv = initd[g] + (dn > 0.f ? acc * INV_SQRT_F * __fdividef(1.0f, dn) : 0.f);
    s_dm[s][g] = dv;
    if (jb == 0) out_dummy[b * 64 + tid] = dv;
  }
  __syncthreads();
  for (int idx = tid; idx < 512; idx += 256) {
    int sh = idx >> 5, g = idx & 31, s = sh >> 3, h = sh & 7;
    const float* wk = &Wkg2[h * 1024 + g];
    const float* wv = &Wvg2[h * 1024 + g];
    float a = 0.f, v = 0.f;
    #pragma unroll
    for (int f = 0; f < 32; f++) { float d = s_dm[s][f]; a += d * wk[f * 32]; v += d * wv[f * 32]; }
    s_Bkg[sh][g] = a;
    s_Bvg[sh][g] = v;
  }
  __syncthreads();
  for (int idx = tid; idx < 512; idx += 256) {
    int f = idx >> 4, sh = idx & 15;
    float a = 0.f;
    #pragma unroll
    for (int g = 0; g < 32; g++) a += s_WQD[f][g] * s_Bkg[sh][g];
    s_G[f][sh] = a * SC_STAGE2;
  }
  __syncthreads();

  const int cnt = ss1 - ss0;
  const int per = (cnt + SL2 - 1) / SL2;
  const int lo = ss0 + tid + jb * per;
  const int hi = min(ss0 + (jb + 1) * per, ss1);

  for (int i = lo; i < hi; i += 256) {
    float z = pos[3 * (size_t)i + 2];
    float len0 = z - zmin + DIST, len1 = zmax + DIST - z;
    float ee[16];
    #pragma unroll
    for (int s = 0; s < 2; s++) {
      float L = s ? len1 : len0;
      float inv = __fdividef(1.0f, L + EPSV);
      #pragma unroll
      for (int j = 0; j < 8; j++) ee[8*s + j] = __sinf(s_bw[j] * L) * inv;
    }
    float hkg[16], hvg[16];
    #pragma unroll
    for (int s = 0; s < 2; s++) {
      #pragma unroll
      for (int h = 0; h < 8; h++) {
        float a = 0.f, v = 0.f;
        #pragma unroll
        for (int j = 0; j < 8; j++) { a += ee[8*s + j] * s_Wa[j][h]; v += ee[8*s + j] * s_Wb[j][h]; }
        hkg[8*s + h] = silu_f(a); hvg[8*s + h] = silu_f(v);
      }
    }
    float xv[32];
    const float4* xp = (const float4*)&xfeat[(size_t)i * 32];
    #pragma unroll
    for (int q = 0; q < 8; q++) { float4 t = xp[q]; xv[4*q] = t.x; xv[4*q+1] = t.y; xv[4*q+2] = t.z; xv[4*q+3] = t.w; }
    float ev[16] = {0,0,0,0,0,0,0,0,0,0,0,0,0,0,0,0};
    #pragma unroll
    for (int f = 0; f < 32; f++) {
      float xf = xv[f];
      #pragma unroll
      for (int sh = 0; sh < 16; sh++) ev[sh] += xf * s_G[f][sh];
    }
    float sc0 = 0.f, sc1 = 0.f;
    #pragma unroll
    for (int h = 0; h < 8; h++) { sc0 += hkg[h] * ev[h]; sc1 += hkg[8 + h] * ev[8 + h]; }
    float m = fmaxf(sc0, sc1);
    float a0 = __expf(sc0 - m), a1 = __expf(sc1 - m);
    float invd = __fdividef(1.0f, a0 + a1);
    float w0 = a0 * invd * INV_SQRT_F, w1 = a1 * invd * INV_SQRT_F;
    float wv[16];
    #pragma unroll
    for (int sh = 0; sh < 16; sh++) wv[sh] = (sh < 8 ? w0 : w1) * hvg[sh];
    float ov[32];
    #pragma unroll
    for (int g = 0; g < 32; g++) ov[g] = xv[g];
    #pragma unroll
    for (int sh = 0; sh < 16; sh++) {
      float w = wv[sh];
      #pragma unroll
      for (int g = 0; g < 32; g++) ov[g] += w * s_Bvg[sh][g];
    }
    float4* op = (float4*)&out_node[(size_t)i * 32];
    #pragma unroll
    for (int q = 0; q < 8; q++) op[q] = make_float4(ov[4*q], ov[4*q+1], ov[4*q+2], ov[4*q+3]);
  }
}

extern "C" void kernel_launch(void* const* d_in, const int* in_sizes, int n_in,
                              void* d_out, int out_size, void* d_ws, size_t ws_size,
                              hipStream_t stream)
{
  const float* pos   = (const float*)d_in[0];
  const int*   batch = (const int*)d_in[1];
  const float* xf    = (const float*)d_in[2];
  const float* bw    = (const float*)d_in[3];
  const float* Wqd   = (const float*)d_in[4];
  const float* Wk1   = (const float*)d_in[5];
  const float* Wk2   = (const float*)d_in[6];
  const float* Wv1   = (const float*)d_in[7];
  const float* Wv2   = (const float*)d_in[8];
  const float* Wqg   = (const float*)d_in[9];
  const float* Wkg1  = (const float*)d_in[10];
  const float* Wkg2  = (const float*)d_in[11];
  const float* Wvg1  = (const float*)d_in[12];
  const float* Wvg2  = (const float*)d_in[13];
  const float* Wdot  = (const float*)d_in[14];
  const float* initd = (const float*)d_in[15];
  int N = in_sizes[1];

  float* out_node  = (float*)d_out;
  float* out_dummy = out_node + (size_t)N * 32;

  // workspace layout (float offsets) — every word written before read, each call
  float* ws      = (float*)d_ws;
  float* ws_Tp   = ws;                        // 32*7*512 = 114688
  float* ws_denp = ws + 114688;               // 448 (+pad)
  float* ws_zf   = ws + 115200;               // 64

  stage1_kernel<<<NBATCH * SL1, 256, 0, stream>>>(pos, batch, xf, bw, Wqd, Wk1, Wk2, Wv1,
                                                  Wdot, initd, ws_Tp, ws_denp, ws_zf, N);

  stage2_kernel<<<NBATCH * SL2, 256, 0, stream>>>(pos, batch, xf, bw, Wqg, Wdot, Wkg1, Wkg2,
                                                  Wvg1, Wvg2, Wv2, initd, ws_Tp, ws_denp,
                                                  ws_zf, out_node, out_dummy, N);
}

// Round 10
// 40.986 us; speedup vs baseline: 1.1361x; 1.1361x over previous
//
#include <hip/hip_runtime.h>

#define NBATCH 32
#define DIST 5.0f
#define EPSV 1e-6f
#define INV_SQRT_F 0.17677669529663687f   // 1/sqrt(32)
#define SC_STAGE2 1.72633492e-4f          // 32^{-5/2}
#define SL1 8     // stage-1 slices per batch -> 256 blocks (per ~196 < 256: single tile)
#define SL2 8     // stage-2 slices per batch -> 256 blocks

__device__ __forceinline__ float silu_f(float v) { return __fdividef(v, 1.0f + __expf(-v)); }

// monotonic float <-> uint mapping for min/max via integer compares
__device__ __forceinline__ unsigned f2key(float f) {
  unsigned u = __float_as_uint(f);
  return (u & 0x80000000u) ? ~u : (u | 0x80000000u);
}
__device__ __forceinline__ float key2f(unsigned k) {
  return (k & 0x80000000u) ? __uint_as_float(k ^ 0x80000000u) : __uint_as_float(~k);
}

// all-threads redundant binary search (no divergence, L2-cached probes)
__device__ __forceinline__ int lower_bound_i(const int* __restrict__ batch, int N, int key) {
  int lo = 0, hi = N;
  while (lo < hi) { int m = (lo + hi) >> 1; if (batch[m] < key) lo = m + 1; else hi = m; }
  return lo;
}

// ---------------- K1: stage-1 fused ----------------
extern "C" __global__ __launch_bounds__(256)
void stage1_kernel(const float* __restrict__ pos,
                   const int*   __restrict__ batch,
                   const float* __restrict__ xfeat,
                   const float* __restrict__ bw,
                   const float* __restrict__ Wqd,
                   const float* __restrict__ Wk1,
                   const float* __restrict__ Wk2,
                   const float* __restrict__ Wv1,
                   const float* __restrict__ Wdot,
                   const float* __restrict__ initd,
                   float* __restrict__ ws_Tp,    // [NB*SL1][512]
                   float* __restrict__ ws_denp,  // [NB*SL1][2]
                   float* __restrict__ ws_zf,    // [NB][2]
                   int N)
{
  const int b = blockIdx.x >> 3, jb = blockIdx.x & 7;
  const int tid = threadIdx.x;
  const int wid = tid >> 6, lane = tid & 63;

  __shared__ float s_bw[8];
  __shared__ float s_q[32], s_c[32];
  __shared__ float s_Wa[8][8], s_Wb[8][8];
  __shared__ float s_Mk[32][8];
  __shared__ float s_exh[256][17];   // pad 17: conflict-free reads
  __shared__ float s_xs[256][36];    // pad 36: float4 rows, conflict-free reads
  __shared__ float s_Tp[4][512];
  __shared__ unsigned s_wmin[4], s_wmax[4];
  __shared__ float s_wd0[4], s_wd1[4];

  // small weight loads + q; binary searches overlap via ILP
  if (tid < 8) s_bw[tid] = bw[tid];
  if (tid < 64) { s_Wa[tid >> 3][tid & 7] = Wk1[tid]; s_Wb[tid >> 3][tid & 7] = Wv1[tid]; }
  if (tid < 32) {
    float a = 0.f;
    #pragma unroll
    for (int f = 0; f < 32; f++) a += initd[f] * Wqd[f * 32 + tid];
    s_q[tid] = a * INV_SQRT_F;
  }
  const int ss0 = lower_bound_i(batch, N, b);
  const int ss1 = lower_bound_i(batch, N, b + 1);
  __syncthreads();
  if (tid < 32) {
    float a = 0.f;
    #pragma unroll
    for (int f = 0; f < 32; f++) a += s_q[f] * Wdot[f * 32 + tid];
    s_c[tid] = a;
  }
  __syncthreads();
  {
    int f = tid >> 3, h = tid & 7;
    const float* w = &Wk2[h * 1024 + f * 32];
    float a = 0.f;
    #pragma unroll
    for (int g = 0; g < 32; g++) a += w[g] * s_c[g];
    s_Mk[f][h] = a * (1.0f / 1024.0f);
  }
  __syncthreads();   // publish s_Mk

  const int cnt = ss1 - ss0;
  const int per = (cnt + SL1 - 1) / SL1;
  const int lo = ss0 + jb * per;
  const int hi = min(lo + per, ss1);

  // ---- first tile: issue x loads + batched z-scan loads together (all in flight) ----
  const int i0 = lo + tid;
  const bool act = i0 < hi;
  float4 xr[8];
  float z0 = 0.f;
  if (act) {
    const float4* xp = (const float4*)&xfeat[(size_t)i0 * 32];
    #pragma unroll
    for (int q = 0; q < 8; q++) xr[q] = xp[q];
    z0 = pos[3 * (size_t)i0 + 2];
  }
  unsigned kmn = 0xFFFFFFFFu, kmx = 0u;
  for (int base = ss0; base < ss1; base += 2048) {
    float zz[8]; int iv[8];
    #pragma unroll
    for (int q = 0; q < 8; q++) {
      int i = base + (q << 8) + tid;
      iv[q] = (i < ss1);
      zz[q] = iv[q] ? pos[3 * (size_t)i + 2] : 0.f;
    }
    #pragma unroll
    for (int q = 0; q < 8; q++) if (iv[q]) {
      unsigned k = f2key(zz[q]);
      kmn = min(kmn, k); kmx = max(kmx, k);
    }
  }
  // unpack x: write s_xs row + compute u (drops xv — low reg pressure after this)
  float u[8] = {0,0,0,0,0,0,0,0};
  if (act) {
    float4* xso = (float4*)s_xs[tid];
    #pragma unroll
    for (int q = 0; q < 8; q++) {
      xso[q] = xr[q];
      float vx0 = xr[q].x, vx1 = xr[q].y, vx2 = xr[q].z, vx3 = xr[q].w;
      #pragma unroll
      for (int h = 0; h < 8; h++)
        u[h] += vx0 * s_Mk[4*q][h] + vx1 * s_Mk[4*q+1][h] + vx2 * s_Mk[4*q+2][h] + vx3 * s_Mk[4*q+3][h];
    }
  } else {
    float4* xso = (float4*)s_xs[tid];
    float4 z4 = make_float4(0.f, 0.f, 0.f, 0.f);
    #pragma unroll
    for (int q = 0; q < 8; q++) xso[q] = z4;
  }
  // wave-shuffle z reduction + 4-entry combine
  #pragma unroll
  for (int m = 32; m >= 1; m >>= 1) {
    kmn = min(kmn, (unsigned)__shfl_xor((int)kmn, m));
    kmx = max(kmx, (unsigned)__shfl_xor((int)kmx, m));
  }
  if (lane == 0) { s_wmin[wid] = kmn; s_wmax[wid] = kmx; }
  __syncthreads();   // publishes s_wmin/s_wmax AND s_xs
  const unsigned rmn = min(min(s_wmin[0], s_wmin[1]), min(s_wmin[2], s_wmin[3]));
  const unsigned rmx = max(max(s_wmax[0], s_wmax[1]), max(s_wmax[2], s_wmax[3]));
  const float zmin = key2f(rmn), zmax = key2f(rmx);

  float Treg[8] = {0,0,0,0,0,0,0,0};
  float d0 = 0.f, d1 = 0.f;
  const int osh = lane >> 2, ofg = lane & 3;

  // first tile: ee/scores/exh
  if (act) {
    float len0 = z0 - zmin + DIST, len1 = zmax + DIST - z0;
    #pragma unroll
    for (int s = 0; s < 2; s++) {
      float L = s ? len1 : len0;
      float inv = __fdividef(1.0f, L + EPSV);
      float ee[8];
      #pragma unroll
      for (int j = 0; j < 8; j++) ee[j] = __sinf(s_bw[j] * L) * inv;
      float sc = 0.f;
      #pragma unroll
      for (int h = 0; h < 8; h++) {
        float a = 0.f;
        #pragma unroll
        for (int j = 0; j < 8; j++) a += ee[j] * s_Wa[j][h];
        sc += silu_f(a) * u[h];
      }
      // softmax without max-subtraction (exact ratio; clamp = overflow guard)
      float ex = __expf(fminf(fmaxf(sc, -60.f), 60.f));
      if (s) d1 += ex; else d0 += ex;
      #pragma unroll
      for (int h = 0; h < 8; h++) {
        float v = 0.f;
        #pragma unroll
        for (int j = 0; j < 8; j++) v += ee[j] * s_Wb[j][h];
        s_exh[tid][8*s + h] = ex * silu_f(v);
      }
    }
  } else {
    #pragma unroll
    for (int h = 0; h < 16; h++) s_exh[tid][h] = 0.f;
  }
  __syncthreads();
  {
    const int cb = wid * 64;
    for (int c = cb; c < cb + 64; c++) {
      float eh = s_exh[c][osh];
      const float4* xr4 = (const float4*)&s_xs[c][ofg * 8];
      float4 xa = xr4[0], xb = xr4[1];
      Treg[0] += eh * xa.x; Treg[1] += eh * xa.y; Treg[2] += eh * xa.z; Treg[3] += eh * xa.w;
      Treg[4] += eh * xb.x; Treg[5] += eh * xb.y; Treg[6] += eh * xb.z; Treg[7] += eh * xb.w;
    }
  }
  __syncthreads();

  // remaining tiles (rare: only if per > 256)
  for (int base = lo + 256; base < hi; base += 256) {
    int i = base + tid;
    if (i < hi) {
      float z = pos[3 * (size_t)i + 2];
      float len0 = z - zmin + DIST, len1 = zmax + DIST - z;
      float xv[32];
      const float4* xp = (const float4*)&xfeat[(size_t)i * 32];
      float4* xso = (float4*)s_xs[tid];
      #pragma unroll
      for (int q = 0; q < 8; q++) {
        float4 t = xp[q];
        xso[q] = t;
        xv[4*q] = t.x; xv[4*q+1] = t.y; xv[4*q+2] = t.z; xv[4*q+3] = t.w;
      }
      float uu[8] = {0,0,0,0,0,0,0,0};
      #pragma unroll
      for (int f = 0; f < 32; f++) {
        float xf = xv[f];
        #pragma unroll
        for (int h = 0; h < 8; h++) uu[h] += xf * s_Mk[f][h];
      }
      #pragma unroll
      for (int s = 0; s < 2; s++) {
        float L = s ? len1 : len0;
        float inv = __fdividef(1.0f, L + EPSV);
        float ee[8];
        #pragma unroll
        for (int j = 0; j < 8; j++) ee[j] = __sinf(s_bw[j] * L) * inv;
        float sc = 0.f;
        #pragma unroll
        for (int h = 0; h < 8; h++) {
          float a = 0.f;
          #pragma unroll
          for (int j = 0; j < 8; j++) a += ee[j] * s_Wa[j][h];
          sc += silu_f(a) * uu[h];
        }
        float ex = __expf(fminf(fmaxf(sc, -60.f), 60.f));
        if (s) d1 += ex; else d0 += ex;
        #pragma unroll
        for (int h = 0; h < 8; h++) {
          float v = 0.f;
          #pragma unroll
          for (int j = 0; j < 8; j++) v += ee[j] * s_Wb[j][h];
          s_exh[tid][8*s + h] = ex * silu_f(v);
        }
      }
    } else {
      #pragma unroll
      for (int h = 0; h < 16; h++) s_exh[tid][h] = 0.f;
      float4* xso = (float4*)s_xs[tid];
      float4 z4 = make_float4(0.f, 0.f, 0.f, 0.f);
      #pragma unroll
      for (int q = 0; q < 8; q++) xso[q] = z4;
    }
    __syncthreads();
    const int cb = wid * 64;
    for (int c = cb; c < cb + 64; c++) {
      float eh = s_exh[c][osh];
      const float4* xr4 = (const float4*)&s_xs[c][ofg * 8];
      float4 xa = xr4[0], xb = xr4[1];
      Treg[0] += eh * xa.x; Treg[1] += eh * xa.y; Treg[2] += eh * xa.z; Treg[3] += eh * xa.w;
      Treg[4] += eh * xb.x; Treg[5] += eh * xb.y; Treg[6] += eh * xb.z; Treg[7] += eh * xb.w;
    }
    __syncthreads();
  }

  // epilogue: T partials + wave-shuffle den reduction
  #pragma unroll
  for (int k = 0; k < 8; k++) s_Tp[wid][osh * 32 + ofg * 8 + k] = Treg[k];
  #pragma unroll
  for (int m = 32; m >= 1; m >>= 1) { d0 += __shfl_xor(d0, m); d1 += __shfl_xor(d1, m); }
  if (lane == 0) { s_wd0[wid] = d0; s_wd1[wid] = d1; }
  __syncthreads();
  const int slot = b * SL1 + jb;
  for (int idx = tid; idx < 512; idx += 256)
    ws_Tp[slot * 512 + idx] = s_Tp[0][idx] + s_Tp[1][idx] + s_Tp[2][idx] + s_Tp[3][idx];
  if (tid == 0) {
    ws_denp[slot * 2 + 0] = s_wd0[0] + s_wd0[1] + s_wd0[2] + s_wd0[3];
    ws_denp[slot * 2 + 1] = s_wd1[0] + s_wd1[1] + s_wd1[2] + s_wd1[3];
    if (jb == 0) { ws_zf[2*b] = zmin; ws_zf[2*b+1] = zmax; }
  }
}

// ---------------- K2: per-batch tables (redundant per block) + stage-2 output ----------------
extern "C" __global__ __launch_bounds__(256)
void stage2_kernel(const float* __restrict__ pos,
                   const int*   __restrict__ batch,
                   const float* __restrict__ xfeat,
                   const float* __restrict__ bw,
                   const float* __restrict__ Wqg,  const float* __restrict__ Wdot,
                   const float* __restrict__ Wkg1, const float* __restrict__ Wkg2,
                   const float* __restrict__ Wvg1, const float* __restrict__ Wvg2,
                   const float* __restrict__ Wv2,  const float* __restrict__ initd,
                   const float* __restrict__ ws_Tp,
                   const float* __restrict__ ws_denp,
                   const float* __restrict__ ws_zf,
                   float* __restrict__ out_node, float* __restrict__ out_dummy,
                   int N)
{
  const int b = blockIdx.x >> 3, jb = blockIdx.x & 7;
  const int tid = threadIdx.x;

  __shared__ float s_bw[8];
  __shared__ float s_Wa[8][8], s_Wb[8][8];
  __shared__ float s_T[512];
  __shared__ float s_den[2];
  __shared__ float s_dp[4][2][32];
  __shared__ float s_dm[2][32];
  __shared__ float s_WQD[32][32];
  __shared__ float s_Bkg[16][32];
  __shared__ float s_Bvg[16][32];
  __shared__ float s_G[32][16];

  if (tid < 8) s_bw[tid] = bw[tid];
  if (tid < 64) { s_Wa[tid >> 3][tid & 7] = Wkg1[tid]; s_Wb[tid >> 3][tid & 7] = Wvg1[tid]; }
  if (tid < 2) {
    float d = 0.f;
    #pragma unroll
    for (int j = 0; j < SL1; j++) d += ws_denp[(b * SL1 + j) * 2 + tid];
    s_den[tid] = d;
  }
  for (int idx = tid; idx < 512; idx += 256) {
    float a = 0.f;
    #pragma unroll
    for (int j = 0; j < SL1; j++) a += ws_Tp[(b * SL1 + j) * 512 + idx];
    s_T[idx] = a;
  }
  for (int idx = tid; idx < 1024; idx += 256) {
    int f = idx >> 5, g = idx & 31;
    float a = 0.f;
    #pragma unroll
    for (int k = 0; k < 32; k++) a += Wqg[f * 32 + k] * Wdot[k * 32 + g];
    s_WQD[f][g] = a;
  }
  const int ss0 = lower_bound_i(batch, N, b);
  const int ss1 = lower_bound_i(batch, N, b + 1);
  const float zmin = ws_zf[2*b], zmax = ws_zf[2*b+1];
  const int cnt = ss1 - ss0;
  const int per = (cnt + SL2 - 1) / SL2;
  const int lo = ss0 + jb * per;
  const int hi = min(ss0 + (jb + 1) * per, ss1);
  const int i0 = lo + tid;
  const float z0 = (i0 < hi) ? pos[3 * (size_t)i0 + 2] : 0.f;  // prefetch z under table chain
  __syncthreads();

  // parallel dummy: thread (fq, s, g) accumulates f in [fq*8, fq*8+8)
  {
    int g = tid & 31, s = (tid >> 5) & 1, fq = tid >> 6;
    float acc = 0.f;
    #pragma unroll
    for (int h = 0; h < 8; h++) {
      #pragma unroll
      for (int f8 = 0; f8 < 8; f8++) {
        int f = fq * 8 + f8;
        acc += s_T[(8 * s + h) * 32 + f] * Wv2[h * 1024 + f * 32 + g];
      }
    }
    s_dp[fq][s][g] = acc;
  }
  __syncthreads();
  if (tid < 64) {
    int s = tid >> 5, g = tid & 31;
    float acc = s_dp[0][s][g] + s_dp[1][s][g] + s_dp[2][s][g] + s_dp[3][s][g];
    float dn = s_den[s];
    float dv = initd[g] + (dn > 0.f ? acc * INV_SQRT_F * __fdividef(1.0f, dn) : 0.f);
    s_dm[s][g] = dv;
    if (jb == 0) out_dummy[b * 64 + tid] = dv;
  }
  __syncthreads();
  for (int idx = tid; idx < 512; idx += 256) {
    int sh = idx >> 5, g = idx & 31, s = sh >> 3, h = sh & 7;
    const float* wk = &Wkg2[h * 1024 + g];
    const float* wv = &Wvg2[h * 1024 + g];
    float a = 0.f, v = 0.f;
    #pragma unroll
    for (int f = 0; f < 32; f++) { float d = s_dm[s][f]; a += d * wk[f * 32]; v += d * wv[f * 32]; }
    s_Bkg[sh][g] = a;
    s_Bvg[sh][g] = v;
  }
  __syncthreads();
  for (int idx = tid; idx < 512; idx += 256) {
    int f = idx >> 4, sh = idx & 15;
    float a = 0.f;
    #pragma unroll
    for (int g = 0; g < 32; g++) a += s_WQD[f][g] * s_Bkg[sh][g];
    s_G[f][sh] = a * SC_STAGE2;
  }
  __syncthreads();

  for (int i = i0; i < hi; i += 256) {
    float z = (i == i0) ? z0 : pos[3 * (size_t)i + 2];
    float len0 = z - zmin + DIST, len1 = zmax + DIST - z;
    float ee[16];
    #pragma unroll
    for (int s = 0; s < 2; s++) {
      float L = s ? len1 : len0;
      float inv = __fdividef(1.0f, L + EPSV);
      #pragma unroll
      for (int j = 0; j < 8; j++) ee[8*s + j] = __sinf(s_bw[j] * L) * inv;
    }
    float hkg[16], hvg[16];
    #pragma unroll
    for (int s = 0; s < 2; s++) {
      #pragma unroll
      for (int h = 0; h < 8; h++) {
        float a = 0.f, v = 0.f;
        #pragma unroll
        for (int j = 0; j < 8; j++) { a += ee[8*s + j] * s_Wa[j][h]; v += ee[8*s + j] * s_Wb[j][h]; }
        hkg[8*s + h] = silu_f(a); hvg[8*s + h] = silu_f(v);
      }
    }
    float xv[32];
    const float4* xp = (const float4*)&xfeat[(size_t)i * 32];
    #pragma unroll
    for (int q = 0; q < 8; q++) { float4 t = xp[q]; xv[4*q] = t.x; xv[4*q+1] = t.y; xv[4*q+2] = t.z; xv[4*q+3] = t.w; }
    float ev[16] = {0,0,0,0,0,0,0,0,0,0,0,0,0,0,0,0};
    #pragma unroll
    for (int f = 0; f < 32; f++) {
      float xf = xv[f];
      #pragma unroll
      for (int sh = 0; sh < 16; sh++) ev[sh] += xf * s_G[f][sh];
    }
    float sc0 = 0.f, sc1 = 0.f;
    #pragma unroll
    for (int h = 0; h < 8; h++) { sc0 += hkg[h] * ev[h]; sc1 += hkg[8 + h] * ev[8 + h]; }
    float m = fmaxf(sc0, sc1);
    float a0 = __expf(sc0 - m), a1 = __expf(sc1 - m);
    float invd = __fdividef(1.0f, a0 + a1);
    float w0 = a0 * invd * INV_SQRT_F, w1 = a1 * invd * INV_SQRT_F;
    float wvv[16];
    #pragma unroll
    for (int sh = 0; sh < 16; sh++) wvv[sh] = (sh < 8 ? w0 : w1) * hvg[sh];
    float ov[32];
    #pragma unroll
    for (int g = 0; g < 32; g++) ov[g] = xv[g];
    #pragma unroll
    for (int sh = 0; sh < 16; sh++) {
      float w = wvv[sh];
      #pragma unroll
      for (int g = 0; g < 32; g++) ov[g] += w * s_Bvg[sh][g];
    }
    float4* op = (float4*)&out_node[(size_t)i * 32];
    #pragma unroll
    for (int q = 0; q < 8; q++) op[q] = make_float4(ov[4*q], ov[4*q+1], ov[4*q+2], ov[4*q+3]);
  }
}

extern "C" void kernel_launch(void* const* d_in, const int* in_sizes, int n_in,
                              void* d_out, int out_size, void* d_ws, size_t ws_size,
                              hipStream_t stream)
{
  const float* pos   = (const float*)d_in[0];
  const int*   batch = (const int*)d_in[1];
  const float* xf    = (const float*)d_in[2];
  const float* bw    = (const float*)d_in[3];
  const float* Wqd   = (const float*)d_in[4];
  const float* Wk1   = (const float*)d_in[5];
  const float* Wk2   = (const float*)d_in[6];
  const float* Wv1   = (const float*)d_in[7];
  const float* Wv2   = (const float*)d_in[8];
  const float* Wqg   = (const float*)d_in[9];
  const float* Wkg1  = (const float*)d_in[10];
  const float* Wkg2  = (const float*)d_in[11];
  const float* Wvg1  = (const float*)d_in[12];
  const float* Wvg2  = (const float*)d_in[13];
  const float* Wdot  = (const float*)d_in[14];
  const float* initd = (const float*)d_in[15];
  int N = in_sizes[1];

  float* out_node  = (float*)d_out;
  float* out_dummy = out_node + (size_t)N * 32;

  // workspace layout (float offsets) — every word written before read, each call
  float* ws      = (float*)d_ws;
  float* ws_Tp   = ws;                        // 32*8*512 = 131072
  float* ws_denp = ws + 131072;               // 512
  float* ws_zf   = ws + 131584;               // 64

  stage1_kernel<<<NBATCH * SL1, 256, 0, stream>>>(pos, batch, xf, bw, Wqd, Wk1, Wk2, Wv1,
                                                  Wdot, initd, ws_Tp, ws_denp, ws_zf, N);

  stage2_kernel<<<NBATCH * SL2, 256, 0, stream>>>(pos, batch, xf, bw, Wqg, Wdot, Wkg1, Wkg2,
                                                  Wvg1, Wvg2, Wv2, initd, ws_Tp, ws_denp,
                                                  ws_zf, out_node, out_dummy, N);
}